// Round 7
// baseline (95.660 us; speedup 1.0000x reference)
//
#include <hip/hip_runtime.h>
#include <stdint.h>

// Trilinear resampler, REPLICATE (clamp) boundary.
// Counting-sort points into 8^3 voxel tiles (no global atomics, 8B packed
// records), then one 256-thread block per 4 tiles: double-buffered LDS
// staging (bf16) with register prefetch of the next tile's voxels+records
// issued before the current tile's compute -> staging latency hidden
// inside the block.
// inputs:  [B, D, H, W, C] fp32   (B=2, D=H=W=128, C=8)
// coords:  [B, GD, GH, GW, 3] fp32, order (d, h, w)
// output:  [B, GD, GH, GW, C] fp32

constexpr int B  = 2;
constexpr int D  = 128;
constexpr int H  = 128;
constexpr int W  = 128;
constexpr int C  = 8;
constexpr int GD = 96;
constexpr int GH = 96;
constexpr int GW = 96;
constexpr long long PTS_PER_B = (long long)GD * GH * GW;   // 884736
constexpr long long NPTS      = (long long)B * PTS_PER_B;  // 1769472
constexpr int NPTS_I = (int)NPTS;                          // < 2^21

// tiles: 8 x 8 x 8 voxels (z,y,x)
constexpr int TPZ = 16, TPY = 16, TPX = 16;
constexpr int NT_PER_B = TPZ * TPY * TPX;       // 4096
constexpr int NT = B * NT_PER_B;                // 8192

// staged region = tile + 1 halo on the high side of each dim
constexpr int RZ = 9, RY = 9, RX = 9;
constexpr int RVOX = RZ * RY * RX;              // 729 voxels (bf16x8 = 16B)

constexpr int TPB_BIN = 1024;
constexpr int PPT     = 8;
constexpr int NB_BIN  = NPTS_I / (TPB_BIN * PPT);   // 216
static_assert(NB_BIN * TPB_BIN * PPT == NPTS_I, "exact tiling");
constexpr int BPT = NT / TPB_BIN;               // 8

constexpr int BUCKETS_PER_BLOCK = 4;
constexpr int NBLK4 = NT / BUCKETS_PER_BLOCK;   // 2048

__device__ __forceinline__ int clampi(int v, int lo, int hi) {
    return min(max(v, lo), hi);
}

__device__ __forceinline__ int tile_of(int b, float zc, float yc, float xc) {
    int z0 = clampi((int)floorf(zc), 0, D - 1);
    int y0 = clampi((int)floorf(yc), 0, H - 1);
    int x0 = clampi((int)floorf(xc), 0, W - 1);
    return (b << 12) | ((z0 >> 3) << 8) | ((y0 >> 3) << 4) | (x0 >> 3);
}

// packed record: bits [0,21) idx | [21,34) qx | [34,47) qy | [47,60) qz
// q* = local coord within tile in 1/1024 voxel units (0..8191)
__device__ __forceinline__ unsigned long long
pack_rec(int i, float zc, float yc, float xc, int b, int& tk)
{
    const int z0 = clampi((int)floorf(zc), 0, D - 1);
    const int y0 = clampi((int)floorf(yc), 0, H - 1);
    const int x0 = clampi((int)floorf(xc), 0, W - 1);
    const int tz = z0 >> 3, ty = y0 >> 3, tx = x0 >> 3;
    tk = (b << 12) | (tz << 8) | (ty << 4) | tx;
    const int qz = clampi((int)((zc - (float)(tz << 3)) * 1024.0f + 0.5f), 0, 8191);
    const int qy = clampi((int)((yc - (float)(ty << 3)) * 1024.0f + 0.5f), 0, 8191);
    const int qx = clampi((int)((xc - (float)(tx << 3)) * 1024.0f + 0.5f), 0, 8191);
    return (unsigned long long)(uint32_t)i
         | ((unsigned long long)qx << 21)
         | ((unsigned long long)qy << 34)
         | ((unsigned long long)qz << 47);
}

// round-to-nearest-even f32 -> bf16 (low 16 bits)
__device__ __forceinline__ uint32_t bf16_rne(float f) {
    uint32_t u = __float_as_uint(f);
    u += 0x7FFFu + ((u >> 16) & 1u);
    return u >> 16;
}
__device__ __forceinline__ uint32_t pack_bf16(float lo, float hi) {
    return bf16_rne(lo) | (bf16_rne(hi) << 16);
}

// ---- K1: per-block LDS histogram -> blockHist[block][NT] (u16) -------------
__global__ __launch_bounds__(TPB_BIN)
void k_hist(const float* __restrict__ coords, uint16_t* __restrict__ blockHist)
{
    __shared__ uint32_t h[NT];                  // 32 KB
    const int t = threadIdx.x;
#pragma unroll
    for (int j = 0; j < BPT; ++j) h[t + j * TPB_BIN] = 0u;
    __syncthreads();

    const int base = blockIdx.x * (TPB_BIN * PPT);
#pragma unroll
    for (int k = 0; k < PPT; ++k) {
        const int i = base + k * TPB_BIN + t;
        const float zc = coords[3 * i + 0];
        const float yc = coords[3 * i + 1];
        const float xc = coords[3 * i + 2];
        const int b = (i >= (int)PTS_PER_B) ? 1 : 0;
        atomicAdd(&h[tile_of(b, zc, yc, xc)], 1u);
    }
    __syncthreads();
#pragma unroll
    for (int j = 0; j < BPT; ++j) {
        const int c = t + j * TPB_BIN;
        blockHist[blockIdx.x * NT + c] = (uint16_t)h[c];
    }
}

// ---- K2a: per-bucket column prefix over block rows --------------------------
__global__ __launch_bounds__(128)
void k_scan_cols(uint16_t* __restrict__ blockHist, uint32_t* __restrict__ bucketTot)
{
    const int c = blockIdx.x * 128 + threadIdx.x;
    uint32_t acc = 0u;
#pragma unroll 8
    for (int r = 0; r < NB_BIN; ++r) {
        const int o = r * NT + c;
        const uint32_t v = blockHist[o];
        blockHist[o] = (uint16_t)acc;
        acc += v;
    }
    bucketTot[c] = acc;
}

// ---- K2b: scan of bucket totals -> bucketBase ------------------------------
__global__ __launch_bounds__(TPB_BIN)
void k_scan_base(const uint32_t* __restrict__ bucketTot, uint32_t* __restrict__ bucketBase)
{
    __shared__ uint32_t ss[TPB_BIN];
    const int t = threadIdx.x;

    uint32_t l[BPT];
    uint32_t ls = 0u;
#pragma unroll
    for (int j = 0; j < BPT; ++j) {
        l[j] = bucketTot[t * BPT + j];
        ls += l[j];
    }
    ss[t] = ls;
    __syncthreads();
    for (int off = 1; off < TPB_BIN; off <<= 1) {
        const uint32_t v = (t >= off) ? ss[t - off] : 0u;
        __syncthreads();
        ss[t] += v;
        __syncthreads();
    }
    uint32_t basev = ss[t] - ls;
#pragma unroll
    for (int j = 0; j < BPT; ++j) {
        bucketBase[t * BPT + j] = basev;
        basev += l[j];
    }
    if (t == TPB_BIN - 1) bucketBase[NT] = (uint32_t)NPTS_I;
}

// ---- K3: scatter packed 8B records via LDS cursors --------------------------
__global__ __launch_bounds__(TPB_BIN)
void k_scatter(const float* __restrict__ coords,
               const uint16_t* __restrict__ blockHist,
               const uint32_t* __restrict__ bucketBase,
               unsigned long long* __restrict__ records)
{
    __shared__ uint32_t cur[NT];                // 32 KB
    const int t = threadIdx.x;
#pragma unroll
    for (int j = 0; j < BPT; ++j) {
        const int c = t + j * TPB_BIN;
        cur[c] = (uint32_t)blockHist[blockIdx.x * NT + c] + bucketBase[c];
    }
    __syncthreads();

    const int base = blockIdx.x * (TPB_BIN * PPT);
#pragma unroll
    for (int k = 0; k < PPT; ++k) {
        const int i = base + k * TPB_BIN + t;
        const float zc = coords[3 * i + 0];
        const float yc = coords[3 * i + 1];
        const float xc = coords[3 * i + 2];
        const int b = (i >= (int)PTS_PER_B) ? 1 : 0;
        int tk;
        const unsigned long long r = pack_rec(i, zc, yc, xc, b, tk);
        const uint32_t slot = atomicAdd(&cur[tk], 1u);   // LDS atomic
        records[slot] = r;
    }
}

// ---- K4: 4 buckets per block, double-buffered LDS, register prefetch -------
__device__ __forceinline__ void
process_rec(unsigned long long r, const uint4* __restrict__ tb,
            float* __restrict__ out)
{
    const int idx = (int)(r & 0x1FFFFFull);
    const int qx  = (int)((r >> 21) & 0x1FFFull);
    const int qy  = (int)((r >> 34) & 0x1FFFull);
    const int qz  = (int)((r >> 47) & 0x1FFFull);
    const int lx = qx >> 10, ly = qy >> 10, lz = qz >> 10;
    const float wx1 = (float)(qx & 1023) * (1.0f / 1024.0f), wx0 = 1.0f - wx1;
    const float wy1 = (float)(qy & 1023) * (1.0f / 1024.0f), wy0 = 1.0f - wy1;
    const float wz1 = (float)(qz & 1023) * (1.0f / 1024.0f), wz0 = 1.0f - wz1;

    const int vi = (lz * RY + ly) * RX + lx;

    float a0 = 0.f, a1 = 0.f, a2 = 0.f, a3 = 0.f;
    float a4 = 0.f, a5 = 0.f, a6 = 0.f, a7 = 0.f;
    const float wzs[2] = {wz0, wz1};
    const float wys[2] = {wy0, wy1};
    const float wxs[2] = {wx0, wx1};

#pragma unroll
    for (int iz = 0; iz < 2; ++iz) {
#pragma unroll
        for (int iy = 0; iy < 2; ++iy) {
#pragma unroll
            for (int ix = 0; ix < 2; ++ix) {
                const float wt = wzs[iz] * wys[iy] * wxs[ix];
                const int cv = vi + (iz * RY + iy) * RX + ix;
                const uint4 rv = tb[cv];
                a0 += wt * __uint_as_float(rv.x << 16);
                a1 += wt * __uint_as_float(rv.x & 0xFFFF0000u);
                a2 += wt * __uint_as_float(rv.y << 16);
                a3 += wt * __uint_as_float(rv.y & 0xFFFF0000u);
                a4 += wt * __uint_as_float(rv.z << 16);
                a5 += wt * __uint_as_float(rv.z & 0xFFFF0000u);
                a6 += wt * __uint_as_float(rv.w << 16);
                a7 += wt * __uint_as_float(rv.w & 0xFFFF0000u);
            }
        }
    }

    float* o = out + (long long)idx * C;
    *reinterpret_cast<float4*>(o)     = make_float4(a0, a1, a2, a3);
    *reinterpret_cast<float4*>(o + 4) = make_float4(a4, a5, a6, a7);
}

__global__ __launch_bounds__(256)
void k_sample_tiled(const float* __restrict__ inp,
                    const unsigned long long* __restrict__ records,
                    const uint32_t* __restrict__ bucketBase,
                    float* __restrict__ out)
{
    __shared__ uint4 tile[2][RVOX];             // 2 * 729 * 16B = 23328 B
    const int t = threadIdx.x;

    // XCD-chunked swizzle over blocks; each block owns 4 consecutive buckets
    // (x-adjacent tiles -> shared halo planes stay in one L2).
    const int gb = ((int)blockIdx.x & 7) * (NBLK4 >> 3) + ((int)blockIdx.x >> 3);
    const int c0 = gb * BUCKETS_PER_BLOCK;

    float4 pv0[3], pv1[3];                      // prefetched voxels (3/thread)
    unsigned long long pr = 0ull;               // prefetched first record
    bool pr_valid = false;

    auto issue_voxels = [&](int c) {
        const int tx = c & 15, ty = (c >> 4) & 15, tz = (c >> 8) & 15, b = c >> 12;
        const int z0r = tz << 3, y0r = ty << 3, x0r = tx << 3;
#pragma unroll
        for (int j = 0; j < 3; ++j) {
            const int v = t + j * 256;
            if (v < RVOX) {
                const int lz = v / (RY * RX);
                const int rr = v - lz * (RY * RX);
                const int ly = rr / RX;
                const int lx = rr - ly * RX;
                const int gz = min(z0r + lz, D - 1);
                const int gy = min(y0r + ly, H - 1);
                const int gx = min(x0r + lx, W - 1);
                const int a = ((((b << 7) | gz) << 7 | gy) << 7 | gx) * C;
                pv0[j] = *reinterpret_cast<const float4*>(inp + a);
                pv1[j] = *reinterpret_cast<const float4*>(inp + a + 4);
            }
        }
    };
    auto issue_rec = [&](int c) {
        const uint32_t s = bucketBase[c];
        const uint32_t e = bucketBase[c + 1];
        const uint32_t i = s + (uint32_t)t;
        pr_valid = (i < e);
        if (pr_valid) pr = records[i];
    };

    issue_voxels(c0);
    issue_rec(c0);

    for (int k = 0; k < BUCKETS_PER_BLOCK; ++k) {
        const int c = c0 + k;
        uint4* tb = tile[k & 1];

        // pack prefetched voxels -> LDS (bf16)
#pragma unroll
        for (int j = 0; j < 3; ++j) {
            const int v = t + j * 256;
            if (v < RVOX) {
                uint4 pk;
                pk.x = pack_bf16(pv0[j].x, pv0[j].y);
                pk.y = pack_bf16(pv0[j].z, pv0[j].w);
                pk.z = pack_bf16(pv1[j].x, pv1[j].y);
                pk.w = pack_bf16(pv1[j].z, pv1[j].w);
                tb[v] = pk;
            }
        }
        const uint32_t s = bucketBase[c];
        const uint32_t e = bucketBase[c + 1];
        const unsigned long long r0 = pr;       // save before re-prefetch
        const bool r0v = pr_valid;
        __syncthreads();

        // issue next bucket's staging while computing this one
        if (k + 1 < BUCKETS_PER_BLOCK) { issue_voxels(c + 1); issue_rec(c + 1); }

        if (r0v) process_rec(r0, tb, out);
        for (uint32_t i = s + (uint32_t)t + 256u; i < e; i += 256u)
            process_rec(records[i], tb, out);
        // no trailing barrier: next iter writes the other LDS buffer; the
        // barrier at the top of iter k+1 orders reuse of this buffer at k+2.
    }
}

// ---- fallback: direct kernel (if ws too small) -----------------------------
__global__ __launch_bounds__(256)
void resample_direct(const float* __restrict__ inp,
                     const float* __restrict__ coords,
                     float* __restrict__ out)
{
    const long long i = (long long)blockIdx.x * blockDim.x + threadIdx.x;
    if (i >= NPTS) return;
    const int b = (i >= PTS_PER_B) ? 1 : 0;
    const float zc = coords[3 * i + 0];
    const float yc = coords[3 * i + 1];
    const float xc = coords[3 * i + 2];
    const float fz = floorf(zc), fy = floorf(yc), fx = floorf(xc);
    const float wz1 = zc - fz, wz0 = 1.0f - wz1;
    const float wy1 = yc - fy, wy0 = 1.0f - wy1;
    const float wx1 = xc - fx, wx0 = 1.0f - wx1;
    const int z0 = clampi((int)fz, 0, D - 1);
    const int y0 = clampi((int)fy, 0, H - 1);
    const int x0 = clampi((int)fx, 0, W - 1);
    const int z1 = min(z0 + 1, D - 1);
    const int y1 = min(y0 + 1, H - 1);
    const int x1 = min(x0 + 1, W - 1);
    float4 acc_lo = make_float4(0.f, 0.f, 0.f, 0.f);
    float4 acc_hi = make_float4(0.f, 0.f, 0.f, 0.f);
    const int   zs[2]  = {z0, z1};
    const int   ys[2]  = {y0, y1};
    const int   xs[2]  = {x0, x1};
    const float wzs[2] = {wz0, wz1};
    const float wys[2] = {wy0, wy1};
    const float wxs[2] = {wx0, wx1};
#pragma unroll
    for (int iz = 0; iz < 2; ++iz)
#pragma unroll
        for (int iy = 0; iy < 2; ++iy)
#pragma unroll
            for (int ix = 0; ix < 2; ++ix) {
                const float wt = wzs[iz] * wys[iy] * wxs[ix];
                const int base = ((((b << 7) | zs[iz]) << 7 | ys[iy]) << 7 | xs[ix]) * C;
                const float4 v0 = *reinterpret_cast<const float4*>(inp + base);
                const float4 v1 = *reinterpret_cast<const float4*>(inp + base + 4);
                acc_lo.x += wt * v0.x;  acc_lo.y += wt * v0.y;
                acc_lo.z += wt * v0.z;  acc_lo.w += wt * v0.w;
                acc_hi.x += wt * v1.x;  acc_hi.y += wt * v1.y;
                acc_hi.z += wt * v1.z;  acc_hi.w += wt * v1.w;
            }
    float* o = out + i * C;
    *reinterpret_cast<float4*>(o)     = acc_lo;
    *reinterpret_cast<float4*>(o + 4) = acc_hi;
}

extern "C" void kernel_launch(void* const* d_in, const int* in_sizes, int n_in,
                              void* d_out, int out_size, void* d_ws, size_t ws_size,
                              hipStream_t stream)
{
    const float* inp    = (const float*)d_in[0];
    const float* coords = (const float*)d_in[1];
    float* out          = (float*)d_out;

    // ws: records u64[NPTS] | blockHist u16[NB_BIN*NT] | bucketBase u32[NT+1]
    //     | bucketTot u32[NT]
    const size_t rec_bytes  = (size_t)NPTS_I * sizeof(unsigned long long); // 14.2 MB
    const size_t hist_bytes = (size_t)NB_BIN * NT * sizeof(uint16_t);      //  3.5 MB
    const size_t base_bytes = (size_t)(NT + 1) * sizeof(uint32_t);
    const size_t tot_bytes  = (size_t)NT * sizeof(uint32_t);
    const size_t needed     = rec_bytes + hist_bytes + base_bytes + tot_bytes;

    if (ws_size < needed) {
        const int nblk = (NPTS_I + 255) / 256;
        resample_direct<<<nblk, 256, 0, stream>>>(inp, coords, out);
        return;
    }

    unsigned long long* records = (unsigned long long*)d_ws;
    uint16_t* blockHist  = (uint16_t*)((char*)d_ws + rec_bytes);
    uint32_t* bucketBase = (uint32_t*)((char*)d_ws + rec_bytes + hist_bytes);
    uint32_t* bucketTot  = (uint32_t*)((char*)d_ws + rec_bytes + hist_bytes + base_bytes);

    k_hist        <<<NB_BIN,   TPB_BIN, 0, stream>>>(coords, blockHist);
    k_scan_cols   <<<NT / 128, 128,     0, stream>>>(blockHist, bucketTot);
    k_scan_base   <<<1,        TPB_BIN, 0, stream>>>(bucketTot, bucketBase);
    k_scatter     <<<NB_BIN,   TPB_BIN, 0, stream>>>(coords, blockHist, bucketBase, records);
    k_sample_tiled<<<NBLK4,    256,     0, stream>>>(inp, records, bucketBase, out);
}

// Round 8
// 86.904 us; speedup vs baseline: 1.1008x; 1.1008x over previous
//
#include <hip/hip_runtime.h>
#include <stdint.h>

// Trilinear resampler, REPLICATE (clamp) boundary.
// Counting-sort points into 8x8x16 voxel tiles (no global atomics, 8B packed
// records, u16 block histograms), then one 256-thread block per tile stages
// tile+halo (9x9x17) into LDS as bf16 and samples its points from LDS.
// Record loads are issued BEFORE staging so their latency hides under it.
// inputs:  [B, D, H, W, C] fp32   (B=2, D=H=W=128, C=8)
// coords:  [B, GD, GH, GW, 3] fp32, order (d, h, w)
// output:  [B, GD, GH, GW, C] fp32

constexpr int B  = 2;
constexpr int D  = 128;
constexpr int H  = 128;
constexpr int W  = 128;
constexpr int C  = 8;
constexpr int GD = 96;
constexpr int GH = 96;
constexpr int GW = 96;
constexpr long long PTS_PER_B = (long long)GD * GH * GW;   // 884736
constexpr long long NPTS      = (long long)B * PTS_PER_B;  // 1769472
constexpr int NPTS_I = (int)NPTS;                          // < 2^21

// tiles: 8 x 8 x 16 voxels (z,y,x)
constexpr int TPZ = 16, TPY = 16, TPX = 8;
constexpr int NT_PER_B = TPZ * TPY * TPX;       // 2048
constexpr int NT = B * NT_PER_B;                // 4096

// staged region = tile + 1 halo on the high side of each dim
constexpr int RZ = 9, RY = 9, RX = 17;
constexpr int RVOX = RZ * RY * RX;              // 1377 voxels (bf16x8 = 16B)

constexpr int TPB_BIN = 1024;
constexpr int PPT     = 8;
constexpr int NB_BIN  = NPTS_I / (TPB_BIN * PPT);   // 216
static_assert(NB_BIN * TPB_BIN * PPT == NPTS_I, "exact tiling");
constexpr int BPT = NT / TPB_BIN;               // 4

__device__ __forceinline__ int clampi(int v, int lo, int hi) {
    return min(max(v, lo), hi);
}

// packed record: [0,21) idx | [21,35) qx (14b) | [35,48) qy (13b) | [48,61) qz (13b)
// q* = local coord within tile in 1/1024 voxel units
__device__ __forceinline__ unsigned long long
pack_rec(int i, float zc, float yc, float xc, int b, int& tk)
{
    const int z0 = clampi((int)floorf(zc), 0, D - 1);
    const int y0 = clampi((int)floorf(yc), 0, H - 1);
    const int x0 = clampi((int)floorf(xc), 0, W - 1);
    const int tz = z0 >> 3, ty = y0 >> 3, tx = x0 >> 4;
    tk = (b << 11) | (tz << 7) | (ty << 3) | tx;
    const int qz = clampi((int)((zc - (float)(tz << 3)) * 1024.0f + 0.5f), 0,  8191);
    const int qy = clampi((int)((yc - (float)(ty << 3)) * 1024.0f + 0.5f), 0,  8191);
    const int qx = clampi((int)((xc - (float)(tx << 4)) * 1024.0f + 0.5f), 0, 16383);
    return (unsigned long long)(uint32_t)i
         | ((unsigned long long)qx << 21)
         | ((unsigned long long)qy << 35)
         | ((unsigned long long)qz << 48);
}

__device__ __forceinline__ int tile_of(int b, float zc, float yc, float xc) {
    int z0 = clampi((int)floorf(zc), 0, D - 1);
    int y0 = clampi((int)floorf(yc), 0, H - 1);
    int x0 = clampi((int)floorf(xc), 0, W - 1);
    return (b << 11) | ((z0 >> 3) << 7) | ((y0 >> 3) << 3) | (x0 >> 4);
}

// round-to-nearest-even f32 -> bf16 (low 16 bits)
__device__ __forceinline__ uint32_t bf16_rne(float f) {
    uint32_t u = __float_as_uint(f);
    u += 0x7FFFu + ((u >> 16) & 1u);
    return u >> 16;
}
__device__ __forceinline__ uint32_t pack_bf16(float lo, float hi) {
    return bf16_rne(lo) | (bf16_rne(hi) << 16);
}

// ---- K1: per-block LDS histogram -> blockHist[block][NT] (u16) -------------
__global__ __launch_bounds__(TPB_BIN)
void k_hist(const float* __restrict__ coords, uint16_t* __restrict__ blockHist)
{
    __shared__ uint32_t h[NT];                  // 16 KB
    const int t = threadIdx.x;
#pragma unroll
    for (int j = 0; j < BPT; ++j) h[t + j * TPB_BIN] = 0u;
    __syncthreads();

    const int base = blockIdx.x * (TPB_BIN * PPT);
#pragma unroll
    for (int k = 0; k < PPT; ++k) {
        const int i = base + k * TPB_BIN + t;
        const float zc = coords[3 * i + 0];
        const float yc = coords[3 * i + 1];
        const float xc = coords[3 * i + 2];
        const int b = (i >= (int)PTS_PER_B) ? 1 : 0;
        atomicAdd(&h[tile_of(b, zc, yc, xc)], 1u);
    }
    __syncthreads();
#pragma unroll
    for (int j = 0; j < BPT; ++j) {
        const int c = t + j * TPB_BIN;
        blockHist[blockIdx.x * NT + c] = (uint16_t)h[c];
    }
}

// ---- K2a: per-bucket column prefix over block rows --------------------------
__global__ __launch_bounds__(128)
void k_scan_cols(uint16_t* __restrict__ blockHist, uint32_t* __restrict__ bucketTot)
{
    const int c = blockIdx.x * 128 + threadIdx.x;
    uint32_t acc = 0u;
#pragma unroll 8
    for (int r = 0; r < NB_BIN; ++r) {
        const int o = r * NT + c;
        const uint32_t v = blockHist[o];
        blockHist[o] = (uint16_t)acc;           // fits u16 (<= bucket total)
        acc += v;
    }
    bucketTot[c] = acc;
}

// ---- K2b: scan of bucket totals -> bucketBase ------------------------------
__global__ __launch_bounds__(TPB_BIN)
void k_scan_base(const uint32_t* __restrict__ bucketTot, uint32_t* __restrict__ bucketBase)
{
    __shared__ uint32_t ss[TPB_BIN];
    const int t = threadIdx.x;

    uint32_t l[BPT];
    uint32_t ls = 0u;
#pragma unroll
    for (int j = 0; j < BPT; ++j) {
        l[j] = bucketTot[t * BPT + j];
        ls += l[j];
    }
    ss[t] = ls;
    __syncthreads();
    for (int off = 1; off < TPB_BIN; off <<= 1) {
        const uint32_t v = (t >= off) ? ss[t - off] : 0u;
        __syncthreads();
        ss[t] += v;
        __syncthreads();
    }
    uint32_t basev = ss[t] - ls;
#pragma unroll
    for (int j = 0; j < BPT; ++j) {
        bucketBase[t * BPT + j] = basev;
        basev += l[j];
    }
    if (t == TPB_BIN - 1) bucketBase[NT] = (uint32_t)NPTS_I;
}

// ---- K3: scatter packed 8B records via LDS cursors --------------------------
__global__ __launch_bounds__(TPB_BIN)
void k_scatter(const float* __restrict__ coords,
               const uint16_t* __restrict__ blockHist,
               const uint32_t* __restrict__ bucketBase,
               unsigned long long* __restrict__ records)
{
    __shared__ uint32_t cur[NT];                // 16 KB
    const int t = threadIdx.x;
#pragma unroll
    for (int j = 0; j < BPT; ++j) {
        const int c = t + j * TPB_BIN;
        cur[c] = (uint32_t)blockHist[blockIdx.x * NT + c] + bucketBase[c];
    }
    __syncthreads();

    const int base = blockIdx.x * (TPB_BIN * PPT);
#pragma unroll
    for (int k = 0; k < PPT; ++k) {
        const int i = base + k * TPB_BIN + t;
        const float zc = coords[3 * i + 0];
        const float yc = coords[3 * i + 1];
        const float xc = coords[3 * i + 2];
        const int b = (i >= (int)PTS_PER_B) ? 1 : 0;
        int tk;
        const unsigned long long r = pack_rec(i, zc, yc, xc, b, tk);
        const uint32_t slot = atomicAdd(&cur[tk], 1u);   // LDS atomic
        records[slot] = r;
    }
}

// ---- K4: one block per bucket; records prefetched before staging -----------
__device__ __forceinline__ void
process_rec(unsigned long long r, const uint4* __restrict__ tb,
            float* __restrict__ out)
{
    const int idx = (int)(r & 0x1FFFFFull);
    const int qx  = (int)((r >> 21) & 0x3FFFull);
    const int qy  = (int)((r >> 35) & 0x1FFFull);
    const int qz  = (int)((r >> 48) & 0x1FFFull);
    const int lx = qx >> 10, ly = qy >> 10, lz = qz >> 10;
    const float wx1 = (float)(qx & 1023) * (1.0f / 1024.0f), wx0 = 1.0f - wx1;
    const float wy1 = (float)(qy & 1023) * (1.0f / 1024.0f), wy0 = 1.0f - wy1;
    const float wz1 = (float)(qz & 1023) * (1.0f / 1024.0f), wz0 = 1.0f - wz1;

    const int vi = (lz * RY + ly) * RX + lx;

    float a0 = 0.f, a1 = 0.f, a2 = 0.f, a3 = 0.f;
    float a4 = 0.f, a5 = 0.f, a6 = 0.f, a7 = 0.f;
    const float wzs[2] = {wz0, wz1};
    const float wys[2] = {wy0, wy1};
    const float wxs[2] = {wx0, wx1};

#pragma unroll
    for (int iz = 0; iz < 2; ++iz) {
#pragma unroll
        for (int iy = 0; iy < 2; ++iy) {
#pragma unroll
            for (int ix = 0; ix < 2; ++ix) {
                const float wt = wzs[iz] * wys[iy] * wxs[ix];
                const int cv = vi + (iz * RY + iy) * RX + ix;
                const uint4 rv = tb[cv];
                a0 += wt * __uint_as_float(rv.x << 16);
                a1 += wt * __uint_as_float(rv.x & 0xFFFF0000u);
                a2 += wt * __uint_as_float(rv.y << 16);
                a3 += wt * __uint_as_float(rv.y & 0xFFFF0000u);
                a4 += wt * __uint_as_float(rv.z << 16);
                a5 += wt * __uint_as_float(rv.z & 0xFFFF0000u);
                a6 += wt * __uint_as_float(rv.w << 16);
                a7 += wt * __uint_as_float(rv.w & 0xFFFF0000u);
            }
        }
    }

    float* o = out + (long long)idx * C;
    *reinterpret_cast<float4*>(o)     = make_float4(a0, a1, a2, a3);
    *reinterpret_cast<float4*>(o + 4) = make_float4(a4, a5, a6, a7);
}

__global__ __launch_bounds__(256)
void k_sample_tiled(const float* __restrict__ inp,
                    const unsigned long long* __restrict__ records,
                    const uint32_t* __restrict__ bucketBase,
                    float* __restrict__ out)
{
    __shared__ uint4 tile[RVOX];                // 1377 * 16B = 22032 B
    const int t = threadIdx.x;

    // XCD-chunked swizzle: consecutive buckets (x-adjacent tiles, shared halo
    // planes) land on the same XCD's L2. NT % 8 == 0 -> bijective.
    const int g = blockIdx.x;
    const int c = (g & 7) * (NT >> 3) + (g >> 3);

    // decode bucket -> (b, tz, ty, tx)
    const int tx = c & 7;
    const int ty = (c >> 3) & 15;
    const int tz = (c >> 7) & 15;
    const int b  = c >> 11;
    const int z0r = tz << 3, y0r = ty << 3, x0r = tx << 4;

    // bucket range + early record prefetch (latency hides under staging)
    const uint32_t s = bucketBase[c];
    const uint32_t e = bucketBase[c + 1];
    const bool v0 = (s + (uint32_t)t        < e);
    const bool v1 = (s + (uint32_t)t + 256u < e);
    unsigned long long r0 = 0ull, r1 = 0ull;
    if (v0) r0 = records[s + (uint32_t)t];
    if (v1) r1 = records[s + (uint32_t)t + 256u];

    // stage region in 2 rounds x 3 voxels/thread (keeps VGPR pressure low)
#pragma unroll
    for (int half = 0; half < 2; ++half) {
        float4 a0[3], a1[3];
#pragma unroll
        for (int j = 0; j < 3; ++j) {
            const int v = t + (half * 3 + j) * 256;
            if (v < RVOX) {
                const int lz = v / (RY * RX);
                const int rr = v - lz * (RY * RX);
                const int ly = rr / RX;
                const int lx = rr - ly * RX;
                const int gz = min(z0r + lz, D - 1);
                const int gy = min(y0r + ly, H - 1);
                const int gx = min(x0r + lx, W - 1);
                const int a = ((((b << 7) | gz) << 7 | gy) << 7 | gx) * C;
                a0[j] = *reinterpret_cast<const float4*>(inp + a);
                a1[j] = *reinterpret_cast<const float4*>(inp + a + 4);
            }
        }
#pragma unroll
        for (int j = 0; j < 3; ++j) {
            const int v = t + (half * 3 + j) * 256;
            if (v < RVOX) {
                uint4 pk;
                pk.x = pack_bf16(a0[j].x, a0[j].y);
                pk.y = pack_bf16(a0[j].z, a0[j].w);
                pk.z = pack_bf16(a1[j].x, a1[j].y);
                pk.w = pack_bf16(a1[j].z, a1[j].w);
                tile[v] = pk;
            }
        }
    }
    __syncthreads();

    if (v0) process_rec(r0, tile, out);
    if (v1) process_rec(r1, tile, out);
    for (uint32_t i = s + (uint32_t)t + 512u; i < e; i += 256u)
        process_rec(records[i], tile, out);
}

// ---- fallback: direct kernel (if ws too small) -----------------------------
__global__ __launch_bounds__(256)
void resample_direct(const float* __restrict__ inp,
                     const float* __restrict__ coords,
                     float* __restrict__ out)
{
    const long long i = (long long)blockIdx.x * blockDim.x + threadIdx.x;
    if (i >= NPTS) return;
    const int b = (i >= PTS_PER_B) ? 1 : 0;
    const float zc = coords[3 * i + 0];
    const float yc = coords[3 * i + 1];
    const float xc = coords[3 * i + 2];
    const float fz = floorf(zc), fy = floorf(yc), fx = floorf(xc);
    const float wz1 = zc - fz, wz0 = 1.0f - wz1;
    const float wy1 = yc - fy, wy0 = 1.0f - wy1;
    const float wx1 = xc - fx, wx0 = 1.0f - wx1;
    const int z0 = clampi((int)fz, 0, D - 1);
    const int y0 = clampi((int)fy, 0, H - 1);
    const int x0 = clampi((int)fx, 0, W - 1);
    const int z1 = min(z0 + 1, D - 1);
    const int y1 = min(y0 + 1, H - 1);
    const int x1 = min(x0 + 1, W - 1);
    float4 acc_lo = make_float4(0.f, 0.f, 0.f, 0.f);
    float4 acc_hi = make_float4(0.f, 0.f, 0.f, 0.f);
    const int   zs[2]  = {z0, z1};
    const int   ys[2]  = {y0, y1};
    const int   xs[2]  = {x0, x1};
    const float wzs[2] = {wz0, wz1};
    const float wys[2] = {wy0, wy1};
    const float wxs[2] = {wx0, wx1};
#pragma unroll
    for (int iz = 0; iz < 2; ++iz)
#pragma unroll
        for (int iy = 0; iy < 2; ++iy)
#pragma unroll
            for (int ix = 0; ix < 2; ++ix) {
                const float wt = wzs[iz] * wys[iy] * wxs[ix];
                const int base = ((((b << 7) | zs[iz]) << 7 | ys[iy]) << 7 | xs[ix]) * C;
                const float4 v0 = *reinterpret_cast<const float4*>(inp + base);
                const float4 v1 = *reinterpret_cast<const float4*>(inp + base + 4);
                acc_lo.x += wt * v0.x;  acc_lo.y += wt * v0.y;
                acc_lo.z += wt * v0.z;  acc_lo.w += wt * v0.w;
                acc_hi.x += wt * v1.x;  acc_hi.y += wt * v1.y;
                acc_hi.z += wt * v1.z;  acc_hi.w += wt * v1.w;
            }
    float* o = out + i * C;
    *reinterpret_cast<float4*>(o)     = acc_lo;
    *reinterpret_cast<float4*>(o + 4) = acc_hi;
}

extern "C" void kernel_launch(void* const* d_in, const int* in_sizes, int n_in,
                              void* d_out, int out_size, void* d_ws, size_t ws_size,
                              hipStream_t stream)
{
    const float* inp    = (const float*)d_in[0];
    const float* coords = (const float*)d_in[1];
    float* out          = (float*)d_out;

    // ws: records u64[NPTS] | blockHist u16[NB_BIN*NT] | bucketBase u32[NT+1]
    //     | bucketTot u32[NT]
    const size_t rec_bytes  = (size_t)NPTS_I * sizeof(unsigned long long); // 14.2 MB
    const size_t hist_bytes = (size_t)NB_BIN * NT * sizeof(uint16_t);      //  1.8 MB
    const size_t base_bytes = (size_t)(NT + 1) * sizeof(uint32_t);
    const size_t tot_bytes  = (size_t)NT * sizeof(uint32_t);
    const size_t needed     = rec_bytes + hist_bytes + base_bytes + tot_bytes;

    if (ws_size < needed) {
        const int nblk = (NPTS_I + 255) / 256;
        resample_direct<<<nblk, 256, 0, stream>>>(inp, coords, out);
        return;
    }

    unsigned long long* records = (unsigned long long*)d_ws;
    uint16_t* blockHist  = (uint16_t*)((char*)d_ws + rec_bytes);
    uint32_t* bucketBase = (uint32_t*)((char*)d_ws + rec_bytes + hist_bytes);
    uint32_t* bucketTot  = (uint32_t*)((char*)d_ws + rec_bytes + hist_bytes + base_bytes);

    k_hist        <<<NB_BIN,   TPB_BIN, 0, stream>>>(coords, blockHist);
    k_scan_cols   <<<NT / 128, 128,     0, stream>>>(blockHist, bucketTot);
    k_scan_base   <<<1,        TPB_BIN, 0, stream>>>(bucketTot, bucketBase);
    k_scatter     <<<NB_BIN,   TPB_BIN, 0, stream>>>(coords, blockHist, bucketBase, records);
    k_sample_tiled<<<NT,       256,     0, stream>>>(inp, records, bucketBase, out);
}